// Round 2
// baseline (114.456 us; speedup 1.0000x reference)
//
#include <hip/hip_runtime.h>
#include <hip/hip_bf16.h>

typedef __attribute__((ext_vector_type(8))) short short8;
typedef __attribute__((ext_vector_type(4))) float f32x4;

#define MFMA16(a, b, c) __builtin_amdgcn_mfma_f32_16x16x32_bf16((a), (b), (c), 0, 0, 0)

__device__ __forceinline__ short f2bf(float f) {
  union { float f; unsigned u; } v; v.f = f;
  unsigned r = v.u + 0x7fffu + ((v.u >> 16) & 1u);   // RNE to bf16
  return (short)(r >> 16);
}

// ---------------------------------------------------------------------------
// K1: QKV projection.  Out[e][pix] = W[e][c] · x[c][pix] + b[e], bf16 outputs.
// Block: 256 thr, covers (b, 256-pixel tile), all 64 e, all 3 tensors.
// A-frags: swizzled b128 from LDS weights. B-frags: u16 gathers from LDS x.
// ---------------------------------------------------------------------------
__global__ __launch_bounds__(256) void qkv_kernel(
    const float* __restrict__ x,
    const float* __restrict__ wq, const float* __restrict__ bq,
    const float* __restrict__ wk, const float* __restrict__ bk,
    const float* __restrict__ wv, const float* __restrict__ bv,
    short* __restrict__ Q, short* __restrict__ K, short* __restrict__ V)
{
  __shared__ alignas(16) short xs[64 * 256];     // [c][pix], linear, 32KB
  __shared__ alignas(16) short ws[3 * 64 * 64];  // [m][e][c ^ ((e&7)<<3)], 24KB
  __shared__ float bs[3 * 64];

  const int t    = threadIdx.x;
  const int b    = blockIdx.x >> 6;
  const int pt   = blockIdx.x & 63;
  const int pix0 = pt << 8;
  const float* xb = x + ((size_t)b << 20);       // b * 64 * 16384

  // stage x tile (fp32 -> bf16), coalesced float4 reads
  #pragma unroll
  for (int i = 0; i < 16; ++i) {
    int f4 = i * 256 + t;                        // 0..4095
    int c  = f4 >> 6;
    int p4 = (f4 & 63) << 2;
    const float4 v = *reinterpret_cast<const float4*>(xb + c * 16384 + pix0 + p4);
    short* d = &xs[c * 256 + p4];
    d[0] = f2bf(v.x); d[1] = f2bf(v.y); d[2] = f2bf(v.z); d[3] = f2bf(v.w);
  }
  // stage weights (swizzled) + biases
  {
    const float* wsrc0 = wq; const float* wsrc1 = wk; const float* wsrc2 = wv;
    #pragma unroll
    for (int i = 0; i < 16; ++i) {
      int idx = i * 256 + t;                     // 0..4095
      int e = idx >> 6, c = idx & 63;
      int d = e * 64 + (c ^ ((e & 7) << 3));
      ws[d]            = f2bf(wsrc0[idx]);
      ws[d + 4096]     = f2bf(wsrc1[idx]);
      ws[d + 8192]     = f2bf(wsrc2[idx]);
    }
    if (t < 192) bs[t] = (t < 64) ? bq[t] : ((t < 128) ? bk[t - 64] : bv[t - 128]);
  }
  __syncthreads();

  const int lane = t & 63;
  const int wid  = t >> 6;          // 0..3
  const int p0   = wid << 6;        // pixel quarter within tile
  const int l15  = lane & 15;
  const int lg   = lane >> 4;       // 0..3

  // B-frags (x^T): shared across the 3 tensors
  short8 bfrag[4][2];
  #pragma unroll
  for (int nt = 0; nt < 4; ++nt) {
    int pix = p0 + nt * 16 + l15;
    #pragma unroll
    for (int ks = 0; ks < 2; ++ks) {
      int cb = ks * 32 + (lg << 3);
      short8 f;
      #pragma unroll
      for (int j = 0; j < 8; ++j) f[j] = xs[(cb + j) * 256 + pix];
      bfrag[nt][ks] = f;
    }
  }

  #pragma unroll
  for (int m = 0; m < 3; ++m) {
    short* op = (m == 0) ? Q : ((m == 1) ? K : V);
    short8 afrag[4][2];
    #pragma unroll
    for (int mt = 0; mt < 4; ++mt) {
      int e = mt * 16 + l15;
      #pragma unroll
      for (int ks = 0; ks < 2; ++ks) {
        int cb8 = (ks * 4 + lg) ^ (e & 7);
        afrag[mt][ks] = *reinterpret_cast<const short8*>(&ws[m * 4096 + e * 64 + cb8 * 8]);
      }
    }
    #pragma unroll
    for (int mt = 0; mt < 4; ++mt) {
      #pragma unroll
      for (int nt = 0; nt < 4; ++nt) {
        f32x4 acc = {0.f, 0.f, 0.f, 0.f};
        acc = MFMA16(afrag[mt][0], bfrag[nt][0], acc);
        acc = MFMA16(afrag[mt][1], bfrag[nt][1], acc);
        int e_base = mt * 16 + (lg << 2);
        int pix = pix0 + p0 + nt * 16 + l15;
        #pragma unroll
        for (int r = 0; r < 4; ++r) {
          int e = e_base + r;
          float val = acc[r] + bs[m * 64 + e];
          op[(((size_t)b * 64 + e) << 14) + pix] = f2bf(val);
        }
      }
    }
  }
}

// ---------------------------------------------------------------------------
// K2: per-(b,e) attention.  512 thr = 8 waves, each owns a 16-row strip.
// LDS slots (XOR-swizzled): LQ (Q then V), LK (K then TV), LT1, LT2 (T2^T).
// ---------------------------------------------------------------------------
__global__ __launch_bounds__(512) void attn_kernel(
    const short* __restrict__ Qg, const short* __restrict__ Kg,
    const short* __restrict__ Vg, float* __restrict__ out)
{
  __shared__ alignas(16) short lds[4 * 16384];   // 128KB
  short* LQ  = lds;
  short* LK  = lds + 16384;
  short* LT1 = lds + 2 * 16384;
  short* LT2 = lds + 3 * 16384;

  const int t = threadIdx.x;
  const size_t base = (size_t)blockIdx.x << 14;  // (b*64+e)*16384

  auto stage = [&](short* dst, const short* src) {
    #pragma unroll
    for (int i = 0; i < 4; ++i) {
      int eb  = i * 512 + t;                     // 16B block id, 0..2047
      int row = eb >> 4;
      int cb  = eb & 15;
      float4 v = *reinterpret_cast<const float4*>(src + (eb << 3));
      *reinterpret_cast<float4*>(dst + row * 128 + ((cb ^ (row & 7)) << 3)) = v;
    }
  };
  stage(LQ, Qg + base);
  stage(LK, Kg + base);
  __syncthreads();

  const int lane = t & 63;
  const int wid  = t >> 6;      // 0..7
  const int m0   = wid << 4;    // row-strip base
  const int l15  = lane & 15;
  const int lg   = lane >> 4;

  // swizzled contiguous fragment (A[m][k] or Bt[n][k], row-major over k)
  auto ldfrag = [&](const short* buf, int rowbase, int ks) -> short8 {
    int row = rowbase + l15;
    int cb  = (ks * 4 + lg) ^ (row & 7);
    return *reinterpret_cast<const short8*>(&buf[row * 128 + cb * 8]);
  };
  // transposed fragment: element (col, k) read from buf[k-row][col] (gather)
  auto ldfragT = [&](const short* buf, int colbase, int ks) -> short8 {
    int col = colbase + l15;
    int kb  = ks * 32 + (lg << 3);
    short8 f;
    #pragma unroll
    for (int j = 0; j < 8; ++j)
      f[j] = buf[(kb + j) * 128 + (col ^ (j << 3))];
    return f;
  };

  f32x4 acc[8];
  short8 af[4];

  auto softmax_store = [&](short* dst) {
    #pragma unroll
    for (int r = 0; r < 4; ++r) {
      float mx = acc[0][r];
      #pragma unroll
      for (int n = 1; n < 8; ++n) mx = fmaxf(mx, acc[n][r]);
      mx = fmaxf(mx, __shfl_xor(mx, 1));
      mx = fmaxf(mx, __shfl_xor(mx, 2));
      mx = fmaxf(mx, __shfl_xor(mx, 4));
      mx = fmaxf(mx, __shfl_xor(mx, 8));
      float p[8]; float s = 0.f;
      #pragma unroll
      for (int n = 0; n < 8; ++n) { p[n] = __expf((acc[n][r] - mx) * 0.125f); s += p[n]; }
      s += __shfl_xor(s, 1); s += __shfl_xor(s, 2);
      s += __shfl_xor(s, 4); s += __shfl_xor(s, 8);
      float inv = 1.0f / s;
      int row = m0 + (lg << 2) + r;
      #pragma unroll
      for (int n = 0; n < 8; ++n) {
        int col = n * 16 + l15;
        dst[row * 128 + (col ^ ((row & 7) << 3))] = f2bf(p[n] * inv);
      }
    }
  };

  // ---- S1 = Q K^T  -> row softmax -> LT1
  #pragma unroll
  for (int ks = 0; ks < 4; ++ks) af[ks] = ldfrag(LQ, m0, ks);
  #pragma unroll
  for (int n = 0; n < 8; ++n) {
    f32x4 a = {0.f, 0.f, 0.f, 0.f};
    #pragma unroll
    for (int ks = 0; ks < 4; ++ks) a = MFMA16(af[ks], ldfrag(LK, n * 16, ks), a);
    acc[n] = a;
  }
  softmax_store(LT1);

  // ---- S2^T = K^T Q -> row softmax -> LT2 (= T2^T)
  #pragma unroll
  for (int ks = 0; ks < 4; ++ks) af[ks] = ldfragT(LK, m0, ks);
  #pragma unroll
  for (int n = 0; n < 8; ++n) {
    f32x4 a = {0.f, 0.f, 0.f, 0.f};
    #pragma unroll
    for (int ks = 0; ks < 4; ++ks) a = MFMA16(af[ks], ldfragT(LQ, n * 16, ks), a);
    acc[n] = a;
  }
  softmax_store(LT2);

  __syncthreads();              // Q,K fully consumed; T1,T2 complete
  stage(LQ, Vg + base);         // V overwrites Q
  __syncthreads();

  // ---- TV = T1 · V  -> bf16 into LK (overwrites K)
  #pragma unroll
  for (int ks = 0; ks < 4; ++ks) af[ks] = ldfrag(LT1, m0, ks);
  #pragma unroll
  for (int n = 0; n < 8; ++n) {
    f32x4 a = {0.f, 0.f, 0.f, 0.f};
    #pragma unroll
    for (int ks = 0; ks < 4; ++ks) a = MFMA16(af[ks], ldfragT(LQ, n * 16, ks), a);
    acc[n] = a;
  }
  #pragma unroll
  for (int n = 0; n < 8; ++n) {
    #pragma unroll
    for (int r = 0; r < 4; ++r) {
      int row = m0 + (lg << 2) + r;
      int col = n * 16 + l15;
      LK[row * 128 + (col ^ ((row & 7) << 3))] = f2bf(acc[n][r]);
    }
  }
  __syncthreads();

  // ---- OUT = TV · T2 = TV · (T2^T)^T : pure NT, write fp32
  #pragma unroll
  for (int ks = 0; ks < 4; ++ks) af[ks] = ldfrag(LK, m0, ks);
  float* ob = out + base;
  #pragma unroll
  for (int n = 0; n < 8; ++n) {
    f32x4 a = {0.f, 0.f, 0.f, 0.f};
    #pragma unroll
    for (int ks = 0; ks < 4; ++ks) a = MFMA16(af[ks], ldfrag(LT2, n * 16, ks), a);
    #pragma unroll
    for (int r = 0; r < 4; ++r) {
      int row = m0 + (lg << 2) + r;
      ob[row * 128 + n * 16 + l15] = a[r];
    }
  }
}

extern "C" void kernel_launch(void* const* d_in, const int* in_sizes, int n_in,
                              void* d_out, int out_size, void* d_ws, size_t ws_size,
                              hipStream_t stream) {
  const float* x  = (const float*)d_in[0];
  const float* wq = (const float*)d_in[1];
  const float* bq = (const float*)d_in[2];
  const float* wk = (const float*)d_in[3];
  const float* bk = (const float*)d_in[4];
  const float* wv = (const float*)d_in[5];
  const float* bv = (const float*)d_in[6];

  const size_t N = (size_t)16 * 64 * 128 * 128;  // 16,777,216 elems per tensor
  short* Q = (short*)d_ws;
  short* K = Q + N;
  short* V = K + N;

  qkv_kernel<<<1024, 256, 0, stream>>>(x, wq, bq, wk, bk, wv, bv, Q, K, V);
  attn_kernel<<<1024, 512, 0, stream>>>(Q, K, V, (float*)d_out);
}

// Round 3
// 92.608 us; speedup vs baseline: 1.2359x; 1.2359x over previous
//
#include <hip/hip_runtime.h>
#include <hip/hip_bf16.h>

typedef __attribute__((ext_vector_type(8))) short short8;
typedef __attribute__((ext_vector_type(4))) float f32x4;

#define MFMA16(a, b, c) __builtin_amdgcn_mfma_f32_16x16x32_bf16((a), (b), (c), 0, 0, 0)

__device__ __forceinline__ short f2bf(float f) {
  union { float f; unsigned u; } v; v.f = f;
  unsigned r = v.u + 0x7fffu + ((v.u >> 16) & 1u);   // RNE to bf16
  return (short)(r >> 16);
}

// ---------------------------------------------------------------------------
// K1: QKV projection.  Out[e][pix] = W[e][c] · x[c][pix] + b[e], bf16 outputs.
// (unchanged from round 2 — ~32µs, near its memory floor; revisit later)
// ---------------------------------------------------------------------------
__global__ __launch_bounds__(256) void qkv_kernel(
    const float* __restrict__ x,
    const float* __restrict__ wq, const float* __restrict__ bq,
    const float* __restrict__ wk, const float* __restrict__ bk,
    const float* __restrict__ wv, const float* __restrict__ bv,
    short* __restrict__ Q, short* __restrict__ K, short* __restrict__ V)
{
  __shared__ alignas(16) short xs[64 * 256];     // [c][pix], linear, 32KB
  __shared__ alignas(16) short ws[3 * 64 * 64];  // [m][e][c ^ ((e&7)<<3)], 24KB
  __shared__ float bs[3 * 64];

  const int t    = threadIdx.x;
  const int b    = blockIdx.x >> 6;
  const int pt   = blockIdx.x & 63;
  const int pix0 = pt << 8;
  const float* xb = x + ((size_t)b << 20);       // b * 64 * 16384

  #pragma unroll
  for (int i = 0; i < 16; ++i) {
    int f4 = i * 256 + t;
    int c  = f4 >> 6;
    int p4 = (f4 & 63) << 2;
    const float4 v = *reinterpret_cast<const float4*>(xb + c * 16384 + pix0 + p4);
    short* d = &xs[c * 256 + p4];
    d[0] = f2bf(v.x); d[1] = f2bf(v.y); d[2] = f2bf(v.z); d[3] = f2bf(v.w);
  }
  {
    #pragma unroll
    for (int i = 0; i < 16; ++i) {
      int idx = i * 256 + t;
      int e = idx >> 6, c = idx & 63;
      int d = e * 64 + (c ^ ((e & 7) << 3));
      ws[d]        = f2bf(wq[idx]);
      ws[d + 4096] = f2bf(wk[idx]);
      ws[d + 8192] = f2bf(wv[idx]);
    }
    if (t < 192) bs[t] = (t < 64) ? bq[t] : ((t < 128) ? bk[t - 64] : bv[t - 128]);
  }
  __syncthreads();

  const int lane = t & 63;
  const int wid  = t >> 6;
  const int p0   = wid << 6;
  const int l15  = lane & 15;
  const int lg   = lane >> 4;

  short8 bfrag[4][2];
  #pragma unroll
  for (int nt = 0; nt < 4; ++nt) {
    int pix = p0 + nt * 16 + l15;
    #pragma unroll
    for (int ks = 0; ks < 2; ++ks) {
      int cb = ks * 32 + (lg << 3);
      short8 f;
      #pragma unroll
      for (int j = 0; j < 8; ++j) f[j] = xs[(cb + j) * 256 + pix];
      bfrag[nt][ks] = f;
    }
  }

  #pragma unroll
  for (int m = 0; m < 3; ++m) {
    short* op = (m == 0) ? Q : ((m == 1) ? K : V);
    short8 afrag[4][2];
    #pragma unroll
    for (int mt = 0; mt < 4; ++mt) {
      int e = mt * 16 + l15;
      #pragma unroll
      for (int ks = 0; ks < 2; ++ks) {
        int cb8 = (ks * 4 + lg) ^ (e & 7);
        afrag[mt][ks] = *reinterpret_cast<const short8*>(&ws[m * 4096 + e * 64 + cb8 * 8]);
      }
    }
    #pragma unroll
    for (int mt = 0; mt < 4; ++mt) {
      #pragma unroll
      for (int nt = 0; nt < 4; ++nt) {
        f32x4 acc = {0.f, 0.f, 0.f, 0.f};
        acc = MFMA16(afrag[mt][0], bfrag[nt][0], acc);
        acc = MFMA16(afrag[mt][1], bfrag[nt][1], acc);
        int e_base = mt * 16 + (lg << 2);
        int pix = pix0 + p0 + nt * 16 + l15;
        #pragma unroll
        for (int r = 0; r < 4; ++r) {
          int e = e_base + r;
          float val = acc[r] + bs[m * 64 + e];
          op[(((size_t)b * 64 + e) << 14) + pix] = f2bf(val);
        }
      }
    }
  }
}

// ---------------------------------------------------------------------------
// K2: per-(b,e) attention.  512 thr = 8 waves, each owns a 16-row strip.
// All MFMA fragments are swizzled ds_read_b128; transposed operands (QT, KT,
// VT) are built ONCE per tile via a per-lane-column transpose (conflict-free
// reads, floor-rate b128 writes) instead of per-fragment u16 gathers.
// Buffer plan (4 x 32KB):
//   B1: Q      -> T1  -> TV     B2: K   -> V
//   B3: KT     -> VT            B4: QT  -> T2^T
// ---------------------------------------------------------------------------
__global__ __launch_bounds__(512) void attn_kernel(
    const short* __restrict__ Qg, const short* __restrict__ Kg,
    const short* __restrict__ Vg, float* __restrict__ out)
{
  __shared__ alignas(16) short lds[4 * 16384];   // 128KB
  short* B1 = lds;
  short* B2 = lds + 16384;
  short* B3 = lds + 2 * 16384;
  short* B4 = lds + 3 * 16384;

  const int t = threadIdx.x;
  const size_t base = (size_t)blockIdx.x << 14;  // (b*64+e)*16384

  // coalesced global rows -> swizzled LDS rows
  auto stage = [&](short* dst, const short* src) {
    #pragma unroll
    for (int i = 0; i < 4; ++i) {
      int eb  = i * 512 + t;                     // 16B block id, 0..2047
      int row = eb >> 4;
      int cb  = eb & 15;
      float4 v = *reinterpret_cast<const float4*>(src + (eb << 3));
      *reinterpret_cast<float4*>(dst + row * 128 + ((cb ^ (row & 7)) << 3)) = v;
    }
  };

  // dst[w][h] = src[h][w]; lane owns column w = t&127, rows rb..rb+31.
  // Reads: 64 lanes sweep 64 consecutive cols of one row -> 2-way (free).
  // Writes: b128 rows of dst, uniform bank coverage (floor).
  auto buildT = [&](short* dst, const short* src) {
    const int w  = t & 127;
    const int rb = (t >> 7) << 5;                // 0,32,64,96
    const int w7 = w & 7;
    const int wg = w >> 3;
    short v[32];
    #pragma unroll
    for (int k = 0; k < 32; ++k) {
      int r = rb + k;
      v[k] = src[r * 128 + ((wg ^ (r & 7)) << 3) + w7];
    }
    #pragma unroll
    for (int k8 = 0; k8 < 4; ++k8) {
      int hb = (rb >> 3) + k8;
      *reinterpret_cast<short8*>(&dst[w * 128 + ((hb ^ w7) << 3)]) =
          *reinterpret_cast<const short8*>(&v[k8 * 8]);
    }
  };

  const int lane = t & 63;
  const int wid  = t >> 6;      // 0..7
  const int m0   = wid << 4;    // row-strip base
  const int l15  = lane & 15;
  const int lg   = lane >> 4;

  auto ldfrag = [&](const short* buf, int rowbase, int ks) -> short8 {
    int row = rowbase + l15;
    int cb  = (ks * 4 + lg) ^ (row & 7);
    return *reinterpret_cast<const short8*>(&buf[row * 128 + cb * 8]);
  };

  f32x4 acc[8];
  short8 af[4];

  // softmax over the 128 cols held as acc[n][r] across 16-lane groups
  auto softmax_inplace = [&]() {
    #pragma unroll
    for (int r = 0; r < 4; ++r) {
      float mx = acc[0][r];
      #pragma unroll
      for (int n = 1; n < 8; ++n) mx = fmaxf(mx, acc[n][r]);
      mx = fmaxf(mx, __shfl_xor(mx, 1));
      mx = fmaxf(mx, __shfl_xor(mx, 2));
      mx = fmaxf(mx, __shfl_xor(mx, 4));
      mx = fmaxf(mx, __shfl_xor(mx, 8));
      float s = 0.f;
      float p[8];
      #pragma unroll
      for (int n = 0; n < 8; ++n) { p[n] = __expf((acc[n][r] - mx) * 0.125f); s += p[n]; }
      s += __shfl_xor(s, 1); s += __shfl_xor(s, 2);
      s += __shfl_xor(s, 4); s += __shfl_xor(s, 8);
      float inv = 1.0f / s;
      #pragma unroll
      for (int n = 0; n < 8; ++n) acc[n][r] = p[n] * inv;
    }
  };

  // write acc (bf16) to own 16-row strip, swizzled
  auto store_strip = [&](short* dst) {
    #pragma unroll
    for (int n = 0; n < 8; ++n) {
      #pragma unroll
      for (int r = 0; r < 4; ++r) {
        int row = m0 + (lg << 2) + r;
        int col = n * 16 + l15;
        dst[row * 128 + (col ^ ((row & 7) << 3))] = f2bf(acc[n][r]);
      }
    }
  };

  // 1. stage Q, K
  stage(B1, Qg + base);
  stage(B2, Kg + base);
  __syncthreads();                               // sync0

  // 2. S1 = Q K^T -> softmax (kept in regs)
  #pragma unroll
  for (int ks = 0; ks < 4; ++ks) af[ks] = ldfrag(B1, m0, ks);
  #pragma unroll
  for (int n = 0; n < 8; ++n) {
    f32x4 a = {0.f, 0.f, 0.f, 0.f};
    #pragma unroll
    for (int ks = 0; ks < 4; ++ks) a = MFMA16(af[ks], ldfrag(B2, n * 16, ks), a);
    acc[n] = a;
  }
  softmax_inplace();
  __syncthreads();                               // sync_a: all S1 reads of B1/B2 done

  // 3. build QT, KT
  buildT(B4, B1);                                // QT
  buildT(B3, B2);                                // KT
  __syncthreads();                               // sync_b

  // 4. T1 -> B1 own strip; V -> B2 (HBM latency hides under S2)
  store_strip(B1);
  stage(B2, Vg + base);

  // 5. S2^T = K^T Q -> softmax (kept in regs)
  #pragma unroll
  for (int ks = 0; ks < 4; ++ks) af[ks] = ldfrag(B3, m0, ks);
  #pragma unroll
  for (int n = 0; n < 8; ++n) {
    f32x4 a = {0.f, 0.f, 0.f, 0.f};
    #pragma unroll
    for (int ks = 0; ks < 4; ++ks) a = MFMA16(af[ks], ldfrag(B4, n * 16, ks), a);
    acc[n] = a;
  }
  softmax_inplace();
  __syncthreads();                               // sync_c: S2 reads done, V staged

  // 6. T2^T -> B4 own strip; build VT (overwrites KT)
  store_strip(B4);
  buildT(B3, B2);                                // VT
  __syncthreads();                               // sync_d

  // 7. TV = T1 · V  (A: B1 own strip, B: VT) -> bounce to B1 own strip
  #pragma unroll
  for (int ks = 0; ks < 4; ++ks) af[ks] = ldfrag(B1, m0, ks);
  #pragma unroll
  for (int n = 0; n < 8; ++n) {
    f32x4 a = {0.f, 0.f, 0.f, 0.f};
    #pragma unroll
    for (int ks = 0; ks < 4; ++ks) a = MFMA16(af[ks], ldfrag(B3, n * 16, ks), a);
    acc[n] = a;
  }
  store_strip(B1);                               // own strip: in-wave RAW->WAR safe

  // 8. OUT = TV · T2 = TV · (T2^T)^T -> fp32 global
  #pragma unroll
  for (int ks = 0; ks < 4; ++ks) af[ks] = ldfrag(B1, m0, ks);
  float* ob = out + base;
  #pragma unroll
  for (int n = 0; n < 8; ++n) {
    f32x4 a = {0.f, 0.f, 0.f, 0.f};
    #pragma unroll
    for (int ks = 0; ks < 4; ++ks) a = MFMA16(af[ks], ldfrag(B4, n * 16, ks), a);
    #pragma unroll
    for (int r = 0; r < 4; ++r) {
      int row = m0 + (lg << 2) + r;
      ob[row * 128 + n * 16 + l15] = a[r];
    }
  }
}

extern "C" void kernel_launch(void* const* d_in, const int* in_sizes, int n_in,
                              void* d_out, int out_size, void* d_ws, size_t ws_size,
                              hipStream_t stream) {
  const float* x  = (const float*)d_in[0];
  const float* wq = (const float*)d_in[1];
  const float* bq = (const float*)d_in[2];
  const float* wk = (const float*)d_in[3];
  const float* bk = (const float*)d_in[4];
  const float* wv = (const float*)d_in[5];
  const float* bv = (const float*)d_in[6];

  const size_t N = (size_t)16 * 64 * 128 * 128;
  short* Q = (short*)d_ws;
  short* K = Q + N;
  short* V = K + N;

  qkv_kernel<<<1024, 256, 0, stream>>>(x, wq, bq, wk, bk, wv, bv, Q, K, V);
  attn_kernel<<<1024, 512, 0, stream>>>(Q, K, V, (float*)d_out);
}